// Round 12
// baseline (7019.060 us; speedup 1.0000x reference)
//
#include <hip/hip_runtime.h>
#include <math.h>

#define TN 1024
#define HH 512
#define BB 256
#define NTHR 512
#define NWREG 96             // dwords (192 fp16, K 0..191) pinned in registers
#define NSTRM 24             // uint4 streamed per step (96 dw, K 192..383)
#define TSTRIDE 136          // fp16 stride of wtail row (272 B, conflict-free)

#define OFF_KEYS 0L
#define OFF_PRS  524288L
#define OFF_HS   1572864L
#define OFF_TM   135790592L

typedef float f32x4 __attribute__((ext_vector_type(4)));
typedef _Float16 f16x2 __attribute__((ext_vector_type(2)));

__device__ __forceinline__ float sigm(float x) { return 1.0f / (1.0f + expf(-x)); }

__device__ __forceinline__ float dot2(unsigned a, unsigned b, float c) {
#if __has_builtin(__builtin_amdgcn_fdot2)
    return __builtin_amdgcn_fdot2(__builtin_bit_cast(f16x2, a),
                                  __builtin_bit_cast(f16x2, b), c, false);
#else
    const f16x2 x = __builtin_bit_cast(f16x2, a);
    const f16x2 y = __builtin_bit_cast(f16x2, b);
    return fmaf((float)x.y, (float)y.y, fmaf((float)x.x, (float)y.x, c));
#endif
}

__device__ __forceinline__ unsigned pack16(float a, float b) {
    f16x2 p; p.x = (_Float16)a; p.y = (_Float16)b;
    return __builtin_bit_cast(unsigned, p);
}

// ---- pre-kernel: w_rec f32 -> fp16 row-major in d_ws ----
__global__ __launch_bounds__(256) void conv_fp16(const float* __restrict__ w,
                                                 _Float16* __restrict__ o) {
    const int i = (blockIdx.x * 256 + threadIdx.x) * 4;
    const f32x4 v = *(const f32x4*)(w + i);
    _Float16 r[4];
    #pragma unroll
    for (int k = 0; k < 4; ++k) r[k] = (_Float16)v[k];
    *(unsigned long long*)(o + i) = *(const unsigned long long*)r;
}

__global__
__attribute__((amdgpu_flat_work_group_size(NTHR, NTHR), amdgpu_waves_per_eu(2, 2)))
void rnn_fused(
    const float* __restrict__ in, const float* __restrict__ w_in,
    const float* __restrict__ b_in, const float* __restrict__ b_rec,
    const float* __restrict__ w_key, const float* __restrict__ b_key,
    const float* __restrict__ z, float* __restrict__ out,
    const _Float16* __restrict__ whf)
{
    __shared__ __align__(16) _Float16 wtail[HH][TSTRIDE];  // 139,264 B: K 384..511
    __shared__ __align__(16) float tbuf[HH][9];            // 18,432 B: hs 8-step tile
    __shared__ __align__(16) _Float16 hsh[HH];             // 1 KB (single buffer)
    __shared__ __align__(16) unsigned wk16[2][256];        // 2 KB: w_key packed fp16
    __shared__ float keysT[2][2][16];
    __shared__ float prsT[2][4][16];
    __shared__ float tmT[2][16];
    __shared__ float inp6[8];

    const int tid = threadIdx.x;
    const int bb  = blockIdx.x;                 // one batch per block
    const int wv  = tid >> 6, ln = tid & 63;
    const float* inb = in + (long)bb * 8 * TN;
    const unsigned* wrow = (const unsigned*)(whf + (long)tid * HH);   // 256 dw

    // ---- weights K 0..191 into registers (static indices), value-pinned ----
    unsigned wreg[NWREG];
    #pragma unroll
    for (int i = 0; i < NWREG / 4; ++i) {
        const uint4 v = *(const uint4*)(wrow + i * 4);
        wreg[i * 4 + 0] = v.x; wreg[i * 4 + 1] = v.y;
        wreg[i * 4 + 2] = v.z; wreg[i * 4 + 3] = v.w;
    }
    #pragma unroll
    for (int i = 0; i < NWREG; ++i) asm volatile("" : "+v"(wreg[i]));

    // ---- weights K 384..511 into LDS (own row) ----
    {
        const uint4* src = (const uint4*)(wrow + 192);       // dw 192..255
        #pragma unroll
        for (int i = 0; i < 16; ++i) *(uint4*)&wtail[tid][i * 8] = src[i];
    }

    // ---- per-lane row constants ----
    const float bs  = b_in[tid] + b_rec[tid];
    const float* wip = w_in + tid * 6;
    const float wi0 = wip[0], wi1 = wip[1], wi2 = wip[2];
    const float wi3 = wip[3], wi4 = wip[4], wi5 = wip[5];

    // ---- init LDS state ----
    hsh[tid] = (_Float16)0.0f;
    tbuf[tid][0] = 0.0f;
    if (tid < 256) {    // packed w_key rows 2tid, 2tid+1
        wk16[0][tid] = pack16(w_key[2 * tid], w_key[2 * tid + 1]);
        wk16[1][tid] = pack16(w_key[HH + 2 * tid], w_key[HH + 2 * tid + 1]);
        // tm_modified[bb,0,:] = tm1
        f32x4 v = *(const f32x4*)(inb + 6 * TN + tid * 4);
        __builtin_nontemporal_store(v, (f32x4*)(out + OFF_TM + (long)bb * 2 * TN + tid * 4));
    }
    if (tid == 0) {
        keysT[0][0][0] = 0.f; keysT[0][1][0] = 0.f;
        prsT[0][0][0] = 0.f; prsT[0][1][0] = 0.f;
        prsT[0][2][0] = 0.f; prsT[0][3][0] = 0.f;
        tmT[0][0] = inb[7 * TN];          // tm2[:,0]
    }
    // argmax(tm1) first-occurrence — wave 0
    int idxm = 0;
    if (wv == 0) {
        const float* tp = inb + 6 * TN;
        float bv = -3.0e38f; int bi = 0;
        for (int i = 0; i < 16; ++i) { int tt = i * 64 + ln; float v = tp[tt]; if (v > bv) { bv = v; bi = tt; } }
        #pragma unroll
        for (int m = 1; m < 64; m <<= 1) {
            float ov = __shfl_xor(bv, m); int oi = __shfl_xor(bi, m);
            if (ov > bv || (ov == bv && oi < bi)) { bv = ov; bi = oi; }
        }
        idxm = bi;
    }
    float kh = 1.0f, off = 0.0f; int side_pre = 1;       // lane-0 carries
    const float bk0 = b_key[0], bk1 = b_key[1];
    __syncthreads();

    // ---------------- time loop ----------------
    for (int t = 1; t < TN; ++t) {
        const int tile = (t >> 4) & 1, sl = t & 15;

        // ---- stage on thread 0 (hidden under GEMV phase) ----
        if (tid == 0) {
            const float q0 = inb[t],          q1 = inb[TN + t];
            const float q2 = inb[2 * TN + t], q3 = inb[3 * TN + t];
            const float q4 = inb[4 * TN + t], q5 = inb[5 * TN + t];
            const float q6 = inb[6 * TN + t], q7 = inb[7 * TN + t];
            const float qz = z[(long)(t - 1) * BB + bb];
            if (t > 1) {
                // direct key(t-1): fp16 h x packed fp16 w_key
                float k0 = 0.f, k1 = 0.f;
                const uint4* h4 = (const uint4*)hsh;
                const uint4* a4 = (const uint4*)&wk16[0][0];
                const uint4* b4 = (const uint4*)&wk16[1][0];
                #pragma unroll 4
                for (int i = 0; i < 64; ++i) {
                    const uint4 hu = h4[i], wa = a4[i], wb = b4[i];
                    k0 = dot2(wa.x, hu.x, k0); k0 = dot2(wa.y, hu.y, k0);
                    k0 = dot2(wa.z, hu.z, k0); k0 = dot2(wa.w, hu.w, k0);
                    k1 = dot2(wb.x, hu.x, k1); k1 = dot2(wb.y, hu.y, k1);
                    k1 = dot2(wb.z, hu.z, k1); k1 = dot2(wb.w, hu.w, k1);
                }
                const float key0 = sigm(k0 + bk0), key1 = sigm(k1 + bk1);
                const int pt = t - 1;
                keysT[(pt >> 4) & 1][0][pt & 15] = key0;
                keysT[(pt >> 4) & 1][1][pt & 15] = key1;
                kh = key0;
            }
            const int side = (kh > 0.5f);
            const float as0 = q2 * kh + q4 * (1.0f - kh);
            const float as1 = q3 * kh + q5 * (1.0f - kh);
            const int closer1 = (fabsf(q0 - q6) <= fabsf(q1 - q6));
            const int done = (t > idxm);
            const int sw = ((side != side_pre) && done && (side != closer1));
            const float t2c = q7 + off;
            if (sw) off += qz * fabsf(0.05f * t2c);
            const float t2e = q7 + off;
            side_pre = side;
            float u0 = (q6 - q0) / (0.15f * q0);    float pr10 = (q6 == 0.f) ? 0.f : u0 * u0;
            float u1 = (q6 - q1) / (0.15f * q1);    float pr11 = (q6 == 0.f) ? 0.f : u1 * u1;
            float u2 = (t2e - as0) / (0.15f * as0); float pr20 = (t2e == 0.f) ? 0.f : u2 * u2;
            float u3 = (t2e - as1) / (0.15f * as1); float pr21 = (t2e == 0.f) ? 0.f : u3 * u3;
            prsT[tile][0][sl] = pr10; prsT[tile][1][sl] = pr11;
            prsT[tile][2][sl] = pr20; prsT[tile][3][sl] = pr21;
            tmT[tile][sl] = t2e;
            inp6[0] = q0; inp6[1] = q1; inp6[2] = as0;
            inp6[3] = as1; inp6[4] = q6; inp6[5] = t2e;
        }

        // ---- GEMV row tid: streamed first (loads issue early), then reg, then LDS ----
        float a0 = 0.f, a1 = 0.f, a2 = 0.f, a3 = 0.f;
        const unsigned* hb = (const unsigned*)hsh;           // 256 dw, wave-uniform
        #pragma unroll
        for (int i = 0; i < NSTRM; ++i) {
            const uint4 wu = *(const uint4*)(wrow + NWREG + i * 4);   // L2 stream
            const uint4 hu = *(const uint4*)(hb + NWREG + i * 4);
            a0 = dot2(wu.x, hu.x, a0); a1 = dot2(wu.y, hu.y, a1);
            a2 = dot2(wu.z, hu.z, a2); a3 = dot2(wu.w, hu.w, a3);
        }
        #pragma unroll
        for (int i = 0; i < NWREG / 4; ++i) {
            const uint4 hu = *(const uint4*)(hb + i * 4);
            a0 = dot2(wreg[i * 4 + 0], hu.x, a0); a1 = dot2(wreg[i * 4 + 1], hu.y, a1);
            a2 = dot2(wreg[i * 4 + 2], hu.z, a2); a3 = dot2(wreg[i * 4 + 3], hu.w, a3);
        }
        #pragma unroll
        for (int i = 0; i < 16; ++i) {
            const uint4 hu = *(const uint4*)(hb + 192 + i * 4);
            const uint4 wu = *(const uint4*)&wtail[tid][i * 8];
            a0 = dot2(wu.x, hu.x, a0); a1 = dot2(wu.y, hu.y, a1);
            a2 = dot2(wu.z, hu.z, a2); a3 = dot2(wu.w, hu.w, a3);
        }
        const float sdot = (a0 + a1) + (a2 + a3);
        __syncthreads();    // A: hsh reads done; inp6/prsT/tmT visible

        // ---- finalize row tid (no reductions) ----
        {
            const float s = sdot + bs
                          + wi0 * inp6[0] + wi1 * inp6[1] + wi2 * inp6[2]
                          + wi3 * inp6[3] + wi4 * inp6[4] + wi5 * inp6[5];
            const float h = tanhf(s);
            hsh[tid] = (_Float16)h;
            tbuf[tid][t & 7] = h;
        }
        __syncthreads();    // D: hsh visible for next step / thread-0 key dot

        // ---- hs flush every 8 steps: each thread flushes ITS OWN row ----
        if ((t & 7) == 7) {
            const int t0 = t - 7;
            const float* tr = &tbuf[tid][0];
            f32x4 v0, v1;
            v0.x = tr[0]; v0.y = tr[1]; v0.z = tr[2]; v0.w = tr[3];
            v1.x = tr[4]; v1.y = tr[5]; v1.z = tr[6]; v1.w = tr[7];
            float* dst = out + OFF_HS + ((long)bb * HH + tid) * TN + t0;
            __builtin_nontemporal_store(v0, (f32x4*)dst);
            __builtin_nontemporal_store(v1, (f32x4*)(dst + 4));
        }
        // ---- keys/prs/tm flush every 16 steps (wave 0) ----
        if ((t & 15) == 0 && wv == 0) {
            const int f = tile ^ 1, t0 = t - 16;
            if (ln < 8) {
                const int ch = ln >> 2, c4 = ln & 3;
                __builtin_nontemporal_store(*(const f32x4*)&keysT[f][ch][c4 * 4],
                    (f32x4*)(out + OFF_KEYS + (long)bb * 2 * TN + ch * TN + t0 + c4 * 4));
            } else if (ln < 24) {
                const int ix = ln - 8, ch = ix >> 2, c4 = ix & 3;
                __builtin_nontemporal_store(*(const f32x4*)&prsT[f][ch][c4 * 4],
                    (f32x4*)(out + OFF_PRS + (long)bb * 4 * TN + ch * TN + t0 + c4 * 4));
            } else if (ln < 28) {
                const int c4 = ln - 24;
                __builtin_nontemporal_store(*(const f32x4*)&tmT[f][c4 * 4],
                    (f32x4*)(out + OFF_TM + (long)bb * 2 * TN + TN + t0 + c4 * 4));
            }
        }
    }

    // ---------------- epilogue: key(1023) + final keys/prs/tm tile ----------------
    if (tid == 0) {
        float k0 = 0.f, k1 = 0.f;
        const uint4* h4 = (const uint4*)hsh;
        const uint4* a4 = (const uint4*)&wk16[0][0];
        const uint4* b4 = (const uint4*)&wk16[1][0];
        #pragma unroll 4
        for (int i = 0; i < 64; ++i) {
            const uint4 hu = h4[i], wa = a4[i], wb = b4[i];
            k0 = dot2(wa.x, hu.x, k0); k0 = dot2(wa.y, hu.y, k0);
            k0 = dot2(wa.z, hu.z, k0); k0 = dot2(wa.w, hu.w, k0);
            k1 = dot2(wb.x, hu.x, k1); k1 = dot2(wb.y, hu.y, k1);
            k1 = dot2(wb.z, hu.z, k1); k1 = dot2(wb.w, hu.w, k1);
        }
        keysT[1][0][15] = sigm(k0 + bk0);
        keysT[1][1][15] = sigm(k1 + bk1);
    }
    __syncthreads();
    if (wv == 0) {
        const int f = 1, t0 = TN - 16;
        if (ln < 8) {
            const int ch = ln >> 2, c4 = ln & 3;
            __builtin_nontemporal_store(*(const f32x4*)&keysT[f][ch][c4 * 4],
                (f32x4*)(out + OFF_KEYS + (long)bb * 2 * TN + ch * TN + t0 + c4 * 4));
        } else if (ln < 24) {
            const int ix = ln - 8, ch = ix >> 2, c4 = ix & 3;
            __builtin_nontemporal_store(*(const f32x4*)&prsT[f][ch][c4 * 4],
                (f32x4*)(out + OFF_PRS + (long)bb * 4 * TN + ch * TN + t0 + c4 * 4));
        } else if (ln < 28) {
            const int c4 = ln - 24;
            __builtin_nontemporal_store(*(const f32x4*)&tmT[f][c4 * 4],
                (f32x4*)(out + OFF_TM + (long)bb * 2 * TN + TN + t0 + c4 * 4));
        }
    }
}

extern "C" void kernel_launch(void* const* d_in, const int* in_sizes, int n_in,
                              void* d_out, int out_size, void* d_ws, size_t ws_size,
                              hipStream_t stream) {
    (void)in_sizes; (void)n_in; (void)out_size; (void)ws_size;
    const float* in    = (const float*)d_in[0];
    const float* w_in  = (const float*)d_in[1];
    const float* b_in  = (const float*)d_in[2];
    const float* w_rec = (const float*)d_in[3];
    const float* b_rec = (const float*)d_in[4];
    const float* w_key = (const float*)d_in[5];
    const float* b_key = (const float*)d_in[6];
    const float* z     = (const float*)d_in[7];
    float* out = (float*)d_out;
    _Float16* whf = (_Float16*)d_ws;     // 512 KB scratch

    hipLaunchKernelGGL(conv_fp16, dim3(HH * HH / 1024), dim3(256), 0, stream, w_rec, whf);
    hipLaunchKernelGGL(rnn_fused, dim3(BB), dim3(NTHR), 0, stream,
                       in, w_in, b_in, b_rec, w_key, b_key, z, out, whf);
}

// Round 13
// 3631.662 us; speedup vs baseline: 1.9327x; 1.9327x over previous
//
#include <hip/hip_runtime.h>
#include <math.h>

#define TN 1024
#define HH 512
#define BB 256
#define NTHR 512
#define NWREG 96             // dwords (192 fp16, K 0..191) pinned in registers
#define NSTRM 24             // uint4 streamed per step (96 dw, K 192..383)
#define TSTRIDE 136          // fp16 stride of wtail row (272 B, conflict-free)

#define OFF_KEYS 0L
#define OFF_PRS  524288L
#define OFF_HS   1572864L
#define OFF_TM   135790592L

typedef float f32x4 __attribute__((ext_vector_type(4)));
typedef _Float16 f16x2 __attribute__((ext_vector_type(2)));

__device__ __forceinline__ float sigm(float x) { return 1.0f / (1.0f + expf(-x)); }

__device__ __forceinline__ float dot2(unsigned a, unsigned b, float c) {
#if __has_builtin(__builtin_amdgcn_fdot2)
    return __builtin_amdgcn_fdot2(__builtin_bit_cast(f16x2, a),
                                  __builtin_bit_cast(f16x2, b), c, false);
#else
    const f16x2 x = __builtin_bit_cast(f16x2, a);
    const f16x2 y = __builtin_bit_cast(f16x2, b);
    return fmaf((float)x.y, (float)y.y, fmaf((float)x.x, (float)y.x, c));
#endif
}

// ---- pre-kernel: w_rec f32 -> fp16 row-major in d_ws ----
__global__ __launch_bounds__(256) void conv_fp16(const float* __restrict__ w,
                                                 _Float16* __restrict__ o) {
    const int i = (blockIdx.x * 256 + threadIdx.x) * 4;
    const f32x4 v = *(const f32x4*)(w + i);
    _Float16 r[4];
    #pragma unroll
    for (int k = 0; k < 4; ++k) r[k] = (_Float16)v[k];
    *(unsigned long long*)(o + i) = *(const unsigned long long*)r;
}

__global__
__attribute__((amdgpu_flat_work_group_size(NTHR, NTHR), amdgpu_waves_per_eu(2, 2)))
void rnn_fused(
    const float* __restrict__ in, const float* __restrict__ w_in,
    const float* __restrict__ b_in, const float* __restrict__ b_rec,
    const float* __restrict__ w_key, const float* __restrict__ b_key,
    const float* __restrict__ z, float* __restrict__ out,
    const _Float16* __restrict__ whf)
{
    __shared__ __align__(16) _Float16 wtail[HH][TSTRIDE];  // 139,264 B: K 384..511
    __shared__ __align__(16) float tbuf[HH][9];            // 18,432 B: hs 8-step tile
    __shared__ __align__(16) _Float16 hsh[2][HH];          // 2 KB
    __shared__ float keysT[2][2][16];
    __shared__ float prsT[2][4][16];
    __shared__ float tmT[2][16];
    __shared__ float inp6[8];
    __shared__ float kred[8][2];

    const int tid = threadIdx.x;
    const int bb  = blockIdx.x;                 // one batch per block
    const int wv  = tid >> 6, ln = tid & 63;
    const float* inb = in + (long)bb * 8 * TN;
    const unsigned* wrow = (const unsigned*)(whf + (long)tid * HH);   // 256 dw

    // ---- weights K 0..191 into registers (static indices), value-pinned ----
    unsigned wreg[NWREG];
    #pragma unroll
    for (int i = 0; i < NWREG / 4; ++i) {
        const uint4 v = *(const uint4*)(wrow + i * 4);
        wreg[i * 4 + 0] = v.x; wreg[i * 4 + 1] = v.y;
        wreg[i * 4 + 2] = v.z; wreg[i * 4 + 3] = v.w;
    }
    #pragma unroll
    for (int i = 0; i < NWREG; ++i) asm volatile("" : "+v"(wreg[i]));

    // ---- weights K 384..511 into LDS (own row) ----
    {
        const uint4* src = (const uint4*)(wrow + 192);       // dw 192..255
        #pragma unroll
        for (int i = 0; i < 16; ++i) *(uint4*)&wtail[tid][i * 8] = src[i];
    }

    // ---- per-lane row constants ----
    const float bs  = b_in[tid] + b_rec[tid];
    const float wk0 = w_key[tid], wk1 = w_key[HH + tid];
    const float* wip = w_in + tid * 6;
    const float wi0 = wip[0], wi1 = wip[1], wi2 = wip[2];
    const float wi3 = wip[3], wi4 = wip[4], wi5 = wip[5];

    // ---- init LDS state ----
    hsh[0][tid] = (_Float16)0.0f;
    tbuf[tid][0] = 0.0f;
    if (tid < 256) {    // tm_modified[bb,0,:] = tm1
        f32x4 v = *(const f32x4*)(inb + 6 * TN + tid * 4);
        __builtin_nontemporal_store(v, (f32x4*)(out + OFF_TM + (long)bb * 2 * TN + tid * 4));
    }
    if (tid == 0) {
        keysT[0][0][0] = 0.f; keysT[0][1][0] = 0.f;
        prsT[0][0][0] = 0.f; prsT[0][1][0] = 0.f;
        prsT[0][2][0] = 0.f; prsT[0][3][0] = 0.f;
        tmT[0][0] = inb[7 * TN];          // tm2[:,0]
    }
    // argmax(tm1) first-occurrence — wave 0
    int idxm = 0;
    if (wv == 0) {
        const float* tp = inb + 6 * TN;
        float bv = -3.0e38f; int bi = 0;
        for (int i = 0; i < 16; ++i) { int tt = i * 64 + ln; float v = tp[tt]; if (v > bv) { bv = v; bi = tt; } }
        #pragma unroll
        for (int m = 1; m < 64; m <<= 1) {
            float ov = __shfl_xor(bv, m); int oi = __shfl_xor(bi, m);
            if (ov > bv || (ov == bv && oi < bi)) { bv = ov; bi = oi; }
        }
        idxm = bi;
    }
    float kh = 1.0f, off = 0.0f; int side_pre = 1;       // lane-0 carries
    const float bk0 = b_key[0], bk1 = b_key[1];
    __syncthreads();

    // ---------------- time loop ----------------
    for (int t = 1; t < TN; ++t) {
        const int par1 = (t - 1) & 1, par2 = t & 1;
        const int tile = (t >> 4) & 1, sl = t & 15;

        // ---- stage on thread 0 (loads issue now; latency hides under GEMV) ----
        if (tid == 0) {
            const float q0 = inb[t],          q1 = inb[TN + t];
            const float q2 = inb[2 * TN + t], q3 = inb[3 * TN + t];
            const float q4 = inb[4 * TN + t], q5 = inb[5 * TN + t];
            const float q6 = inb[6 * TN + t], q7 = inb[7 * TN + t];
            const float qz = z[(long)(t - 1) * BB + bb];
            if (t > 1) {
                float k0 = 0.f, k1 = 0.f;
                #pragma unroll
                for (int w = 0; w < 8; ++w) { k0 += kred[w][0]; k1 += kred[w][1]; }
                const float key0 = sigm(k0 + bk0), key1 = sigm(k1 + bk1);
                const int pt = t - 1;
                keysT[(pt >> 4) & 1][0][pt & 15] = key0;
                keysT[(pt >> 4) & 1][1][pt & 15] = key1;
                kh = key0;
            }
            const int side = (kh > 0.5f);
            const float as0 = q2 * kh + q4 * (1.0f - kh);
            const float as1 = q3 * kh + q5 * (1.0f - kh);
            const int closer1 = (fabsf(q0 - q6) <= fabsf(q1 - q6));
            const int done = (t > idxm);
            const int sw = ((side != side_pre) && done && (side != closer1));
            const float t2c = q7 + off;
            if (sw) off += qz * fabsf(0.05f * t2c);
            const float t2e = q7 + off;
            side_pre = side;
            float u0 = (q6 - q0) / (0.15f * q0);    float pr10 = (q6 == 0.f) ? 0.f : u0 * u0;
            float u1 = (q6 - q1) / (0.15f * q1);    float pr11 = (q6 == 0.f) ? 0.f : u1 * u1;
            float u2 = (t2e - as0) / (0.15f * as0); float pr20 = (t2e == 0.f) ? 0.f : u2 * u2;
            float u3 = (t2e - as1) / (0.15f * as1); float pr21 = (t2e == 0.f) ? 0.f : u3 * u3;
            prsT[tile][0][sl] = pr10; prsT[tile][1][sl] = pr11;
            prsT[tile][2][sl] = pr20; prsT[tile][3][sl] = pr21;
            tmT[tile][sl] = t2e;
            inp6[0] = q0; inp6[1] = q1; inp6[2] = as0;
            inp6[3] = as1; inp6[4] = q6; inp6[5] = t2e;
        }

        // ---- GEMV row tid: streamed loads issued FIRST, latency drains under
        //      the pinned-register and LDS-tail dot work ----
        float a0 = 0.f, a1 = 0.f, a2 = 0.f, a3 = 0.f;
        const unsigned* hb = (const unsigned*)&hsh[par1][0];     // wave-uniform
        #pragma unroll
        for (int i = 0; i < NSTRM; ++i) {                        // streamed dw 96..191
            const uint4 wu = *(const uint4*)(wrow + NWREG + i * 4);
            const uint4 hu = *(const uint4*)(hb + NWREG + i * 4);
            a0 = dot2(wu.x, hu.x, a0); a1 = dot2(wu.y, hu.y, a1);
            a2 = dot2(wu.z, hu.z, a2); a3 = dot2(wu.w, hu.w, a3);
        }
        #pragma unroll
        for (int i = 0; i < NWREG / 4; ++i) {                    // pinned dw 0..95
            const uint4 hu = *(const uint4*)(hb + i * 4);
            a0 = dot2(wreg[i * 4 + 0], hu.x, a0); a1 = dot2(wreg[i * 4 + 1], hu.y, a1);
            a2 = dot2(wreg[i * 4 + 2], hu.z, a2); a3 = dot2(wreg[i * 4 + 3], hu.w, a3);
        }
        #pragma unroll
        for (int i = 0; i < 16; ++i) {                           // LDS tail dw 192..255
            const uint4 hu = *(const uint4*)(hb + 192 + i * 4);
            const uint4 wu = *(const uint4*)&wtail[tid][i * 8];
            a0 = dot2(wu.x, hu.x, a0); a1 = dot2(wu.y, hu.y, a1);
            a2 = dot2(wu.z, hu.z, a2); a3 = dot2(wu.w, hu.w, a3);
        }
        const float sdot = (a0 + a1) + (a2 + a3);
        __syncthreads();    // A: hsh[par1] reads done; inp6/prsT/tmT visible

        // ---- finalize row tid ----
        {
            const float s = sdot + bs
                          + wi0 * inp6[0] + wi1 * inp6[1] + wi2 * inp6[2]
                          + wi3 * inp6[3] + wi4 * inp6[4] + wi5 * inp6[5];
            const float h = tanhf(s);
            hsh[par2][tid] = (_Float16)h;
            tbuf[tid][t & 7] = h;
            float ka0 = h * wk0, ka1 = h * wk1;
            #pragma unroll
            for (int m = 1; m < 64; m <<= 1) { ka0 += __shfl_xor(ka0, m); ka1 += __shfl_xor(ka1, m); }
            if (ln == 0) { kred[wv][0] = ka0; kred[wv][1] = ka1; }
        }
        __syncthreads();    // D: hsh[par2]/kred/tbuf visible

        // ---- hs flush every 8 steps: each thread flushes ITS OWN row ----
        if ((t & 7) == 7) {
            const int t0 = t - 7;
            const float* tr = &tbuf[tid][0];
            f32x4 v0, v1;
            v0.x = tr[0]; v0.y = tr[1]; v0.z = tr[2]; v0.w = tr[3];
            v1.x = tr[4]; v1.y = tr[5]; v1.z = tr[6]; v1.w = tr[7];
            float* dst = out + OFF_HS + ((long)bb * HH + tid) * TN + t0;
            __builtin_nontemporal_store(v0, (f32x4*)dst);
            __builtin_nontemporal_store(v1, (f32x4*)(dst + 4));
        }
        // ---- keys/prs/tm flush every 16 steps (wave 0) ----
        if ((t & 15) == 0 && wv == 0) {
            const int f = tile ^ 1, t0 = t - 16;
            if (ln < 8) {
                const int ch = ln >> 2, c4 = ln & 3;
                __builtin_nontemporal_store(*(const f32x4*)&keysT[f][ch][c4 * 4],
                    (f32x4*)(out + OFF_KEYS + (long)bb * 2 * TN + ch * TN + t0 + c4 * 4));
            } else if (ln < 24) {
                const int ix = ln - 8, ch = ix >> 2, c4 = ix & 3;
                __builtin_nontemporal_store(*(const f32x4*)&prsT[f][ch][c4 * 4],
                    (f32x4*)(out + OFF_PRS + (long)bb * 4 * TN + ch * TN + t0 + c4 * 4));
            } else if (ln < 28) {
                const int c4 = ln - 24;
                __builtin_nontemporal_store(*(const f32x4*)&tmT[f][c4 * 4],
                    (f32x4*)(out + OFF_TM + (long)bb * 2 * TN + TN + t0 + c4 * 4));
            }
        }
    }

    // ---------------- epilogue: key(1023) + final keys/prs/tm tile ----------------
    if (tid == 0) {
        float k0 = 0.f, k1 = 0.f;
        #pragma unroll
        for (int w = 0; w < 8; ++w) { k0 += kred[w][0]; k1 += kred[w][1]; }
        keysT[1][0][15] = sigm(k0 + bk0);
        keysT[1][1][15] = sigm(k1 + bk1);
    }
    __syncthreads();
    if (wv == 0) {
        const int f = 1, t0 = TN - 16;
        if (ln < 8) {
            const int ch = ln >> 2, c4 = ln & 3;
            __builtin_nontemporal_store(*(const f32x4*)&keysT[f][ch][c4 * 4],
                (f32x4*)(out + OFF_KEYS + (long)bb * 2 * TN + ch * TN + t0 + c4 * 4));
        } else if (ln < 24) {
            const int ix = ln - 8, ch = ix >> 2, c4 = ix & 3;
            __builtin_nontemporal_store(*(const f32x4*)&prsT[f][ch][c4 * 4],
                (f32x4*)(out + OFF_PRS + (long)bb * 4 * TN + ch * TN + t0 + c4 * 4));
        } else if (ln < 28) {
            const int c4 = ln - 24;
            __builtin_nontemporal_store(*(const f32x4*)&tmT[f][c4 * 4],
                (f32x4*)(out + OFF_TM + (long)bb * 2 * TN + TN + t0 + c4 * 4));
        }
    }
}

extern "C" void kernel_launch(void* const* d_in, const int* in_sizes, int n_in,
                              void* d_out, int out_size, void* d_ws, size_t ws_size,
                              hipStream_t stream) {
    (void)in_sizes; (void)n_in; (void)out_size; (void)ws_size;
    const float* in    = (const float*)d_in[0];
    const float* w_in  = (const float*)d_in[1];
    const float* b_in  = (const float*)d_in[2];
    const float* w_rec = (const float*)d_in[3];
    const float* b_rec = (const float*)d_in[4];
    const float* w_key = (const float*)d_in[5];
    const float* b_key = (const float*)d_in[6];
    const float* z     = (const float*)d_in[7];
    float* out = (float*)d_out;
    _Float16* whf = (_Float16*)d_ws;     // 512 KB scratch

    hipLaunchKernelGGL(conv_fp16, dim3(HH * HH / 1024), dim3(256), 0, stream, w_rec, whf);
    hipLaunchKernelGGL(rnn_fused, dim3(BB), dim3(NTHR), 0, stream,
                       in, w_in, b_in, b_rec, w_key, b_key, z, out, whf);
}

// Round 14
// 3431.180 us; speedup vs baseline: 2.0457x; 1.0584x over previous
//
#include <hip/hip_runtime.h>
#include <math.h>

#define TN 1024
#define HH 512
#define BB 256
#define NTHR 512
#define NWREG 96             // dwords (192 fp16, K 0..191) pinned in registers
#define NSTRM 24             // uint4 streamed per step (96 dw, K 192..383)
#define TSTRIDE 136          // fp16 stride of wtail row (272 B, conflict-free)

#define OFF_KEYS 0L
#define OFF_PRS  524288L
#define OFF_HS   1572864L
#define OFF_TM   135790592L

typedef float f32x4 __attribute__((ext_vector_type(4)));
typedef _Float16 f16x2 __attribute__((ext_vector_type(2)));

__device__ __forceinline__ float sigm(float x) { return 1.0f / (1.0f + expf(-x)); }

__device__ __forceinline__ float dot2(unsigned a, unsigned b, float c) {
#if __has_builtin(__builtin_amdgcn_fdot2)
    return __builtin_amdgcn_fdot2(__builtin_bit_cast(f16x2, a),
                                  __builtin_bit_cast(f16x2, b), c, false);
#else
    const f16x2 x = __builtin_bit_cast(f16x2, a);
    const f16x2 y = __builtin_bit_cast(f16x2, b);
    return fmaf((float)x.y, (float)y.y, fmaf((float)x.x, (float)y.x, c));
#endif
}

// ---- pre-kernel: w_rec f32 -> fp16 row-major in d_ws ----
__global__ __launch_bounds__(256) void conv_fp16(const float* __restrict__ w,
                                                 _Float16* __restrict__ o) {
    const int i = (blockIdx.x * 256 + threadIdx.x) * 4;
    const f32x4 v = *(const f32x4*)(w + i);
    _Float16 r[4];
    #pragma unroll
    for (int k = 0; k < 4; ++k) r[k] = (_Float16)v[k];
    *(unsigned long long*)(o + i) = *(const unsigned long long*)r;
}

__global__
__attribute__((amdgpu_flat_work_group_size(NTHR, NTHR), amdgpu_waves_per_eu(2, 2)))
void rnn_fused(
    const float* __restrict__ in, const float* __restrict__ w_in,
    const float* __restrict__ b_in, const float* __restrict__ b_rec,
    const float* __restrict__ w_key, const float* __restrict__ b_key,
    const float* __restrict__ z, float* __restrict__ out,
    const _Float16* __restrict__ whf)
{
    __shared__ __align__(16) _Float16 wtail[HH][TSTRIDE];  // 139,264 B: K 384..511
    __shared__ __align__(16) float tbuf[HH][9];            // 18,432 B: hs 8-step tile
    __shared__ __align__(16) _Float16 hsh[2][HH];          // 2 KB (double buffer)
    __shared__ float keysT[2][2][16];
    __shared__ float prsT[2][4][16];
    __shared__ float tmT[2][16];
    __shared__ float kred[8][2];

    const int tid = threadIdx.x;
    const int bb  = blockIdx.x;                 // one batch per block
    const int wv  = tid >> 6, ln = tid & 63;
    const float* inb = in + (long)bb * 8 * TN;
    const unsigned* wrow = (const unsigned*)(whf + (long)tid * HH);   // 256 dw

    // ---- weights K 0..191 into registers (static indices), value-pinned ----
    unsigned wreg[NWREG];
    #pragma unroll
    for (int i = 0; i < NWREG / 4; ++i) {
        const uint4 v = *(const uint4*)(wrow + i * 4);
        wreg[i * 4 + 0] = v.x; wreg[i * 4 + 1] = v.y;
        wreg[i * 4 + 2] = v.z; wreg[i * 4 + 3] = v.w;
    }
    #pragma unroll
    for (int i = 0; i < NWREG; ++i) asm volatile("" : "+v"(wreg[i]));

    // ---- weights K 384..511 into LDS (own row) ----
    {
        const uint4* src = (const uint4*)(wrow + 192);       // dw 192..255
        #pragma unroll
        for (int i = 0; i < 16; ++i) *(uint4*)&wtail[tid][i * 8] = src[i];
    }

    // ---- per-lane row constants ----
    const float bs  = b_in[tid] + b_rec[tid];
    const float wk0 = w_key[tid], wk1 = w_key[HH + tid];
    const float* wip = w_in + tid * 6;
    const float wi0 = wip[0], wi1 = wip[1], wi2 = wip[2];
    const float wi3 = wip[3], wi4 = wip[4], wi5 = wip[5];

    // ---- init LDS state ----
    hsh[0][tid] = (_Float16)0.0f;
    tbuf[tid][0] = 0.0f;
    if (tid < 256) {    // tm_modified[bb,0,:] = tm1
        f32x4 v = *(const f32x4*)(inb + 6 * TN + tid * 4);
        __builtin_nontemporal_store(v, (f32x4*)(out + OFF_TM + (long)bb * 2 * TN + tid * 4));
    }
    if (tid == 0) {
        keysT[0][0][0] = 0.f; keysT[0][1][0] = 0.f;
        prsT[0][0][0] = 0.f; prsT[0][1][0] = 0.f;
        prsT[0][2][0] = 0.f; prsT[0][3][0] = 0.f;
        tmT[0][0] = inb[7 * TN];          // tm2[:,0]
    }
    // argmax(tm1) first-occurrence — every wave computes the identical result
    int idxm;
    {
        const float* tp = inb + 6 * TN;
        float bv = -3.0e38f; int bi = 0;
        for (int i = 0; i < 16; ++i) { int tt = i * 64 + ln; float v = tp[tt]; if (v > bv) { bv = v; bi = tt; } }
        #pragma unroll
        for (int m = 1; m < 64; m <<= 1) {
            float ov = __shfl_xor(bv, m); int oi = __shfl_xor(bi, m);
            if (ov > bv || (ov == bv && oi < bi)) { bv = ov; bi = oi; }
        }
        idxm = bi;
    }
    // per-thread stage carries (bit-identical across threads: deterministic fp32)
    float kh = 1.0f, off = 0.0f; int side_pre = 1;
    const float bk0 = b_key[0], bk1 = b_key[1];
    __syncthreads();

    // ---------------- time loop: ONE barrier per step ----------------
    for (int t = 1; t < TN; ++t) {
        const int par1 = (t - 1) & 1, par2 = t & 1;
        const int tile = (t >> 4) & 1, sl = t & 15;

        // ---- stage, redundantly on EVERY thread (broadcast loads, ~50 VALU) ----
        float win_dot;
        {
            const float q0 = inb[t],          q1 = inb[TN + t];
            const float q2 = inb[2 * TN + t], q3 = inb[3 * TN + t];
            const float q4 = inb[4 * TN + t], q5 = inb[5 * TN + t];
            const float q6 = inb[6 * TN + t], q7 = inb[7 * TN + t];
            const float qz = z[(long)(t - 1) * BB + bb];
            if (t > 1) {
                float k0 = 0.f, k1 = 0.f;
                #pragma unroll
                for (int w = 0; w < 8; ++w) { k0 += kred[w][0]; k1 += kred[w][1]; }
                const float key0 = sigm(k0 + bk0);
                kh = key0;
                if (tid == 0) {
                    const float key1 = sigm(k1 + bk1);
                    const int pt = t - 1;
                    keysT[(pt >> 4) & 1][0][pt & 15] = key0;
                    keysT[(pt >> 4) & 1][1][pt & 15] = key1;
                }
            }
            const int side = (kh > 0.5f);
            const float as0 = q2 * kh + q4 * (1.0f - kh);
            const float as1 = q3 * kh + q5 * (1.0f - kh);
            const int closer1 = (fabsf(q0 - q6) <= fabsf(q1 - q6));
            const int done = (t > idxm);
            const int sw = ((side != side_pre) && done && (side != closer1));
            const float t2c = q7 + off;
            if (sw) off += qz * fabsf(0.05f * t2c);
            const float t2e = q7 + off;
            side_pre = side;
            if (tid == 0) {
                float u0 = (q6 - q0) / (0.15f * q0);    float pr10 = (q6 == 0.f) ? 0.f : u0 * u0;
                float u1 = (q6 - q1) / (0.15f * q1);    float pr11 = (q6 == 0.f) ? 0.f : u1 * u1;
                float u2 = (t2e - as0) / (0.15f * as0); float pr20 = (t2e == 0.f) ? 0.f : u2 * u2;
                float u3 = (t2e - as1) / (0.15f * as1); float pr21 = (t2e == 0.f) ? 0.f : u3 * u3;
                prsT[tile][0][sl] = pr10; prsT[tile][1][sl] = pr11;
                prsT[tile][2][sl] = pr20; prsT[tile][3][sl] = pr21;
                tmT[tile][sl] = t2e;
            }
            // fold the w_in contribution into ONE carried register
            win_dot = wi0 * q0 + wi1 * q1 + wi2 * as0 + wi3 * as1 + wi4 * q6 + wi5 * t2e;
        }

        // ---- GEMV row tid: 24 streamed uint4 + 96 dw pinned + 64 dw LDS tail ----
        float a0 = 0.f, a1 = 0.f, a2 = 0.f, a3 = 0.f;
        const unsigned* hb = (const unsigned*)&hsh[par1][0];     // wave-uniform broadcast
        #pragma unroll
        for (int i = 0; i < NSTRM; ++i) {                        // streamed dw 96..191
            const uint4 wu = *(const uint4*)(wrow + NWREG + i * 4);
            const uint4 hu = *(const uint4*)(hb + NWREG + i * 4);
            a0 = dot2(wu.x, hu.x, a0); a1 = dot2(wu.y, hu.y, a1);
            a2 = dot2(wu.z, hu.z, a2); a3 = dot2(wu.w, hu.w, a3);
        }
        #pragma unroll
        for (int i = 0; i < NWREG / 4; ++i) {                    // pinned dw 0..95
            const uint4 hu = *(const uint4*)(hb + i * 4);
            a0 = dot2(wreg[i * 4 + 0], hu.x, a0); a1 = dot2(wreg[i * 4 + 1], hu.y, a1);
            a2 = dot2(wreg[i * 4 + 2], hu.z, a2); a3 = dot2(wreg[i * 4 + 3], hu.w, a3);
        }
        #pragma unroll
        for (int i = 0; i < 16; ++i) {                           // LDS tail dw 192..255
            const uint4 hu = *(const uint4*)(hb + 192 + i * 4);
            const uint4 wu = *(const uint4*)&wtail[tid][i * 8];
            a0 = dot2(wu.x, hu.x, a0); a1 = dot2(wu.y, hu.y, a1);
            a2 = dot2(wu.z, hu.z, a2); a3 = dot2(wu.w, hu.w, a3);
        }
        const float sdot = (a0 + a1) + (a2 + a3);

        // ---- finalize row tid (no mid-step barrier: hsh is double-buffered,
        //      win_dot is thread-local, kred ordering via the end barrier) ----
        {
            const float s = sdot + bs + win_dot;
            const float h = tanhf(s);
            hsh[par2][tid] = (_Float16)h;
            tbuf[tid][t & 7] = h;
            float ka0 = h * wk0, ka1 = h * wk1;
            #pragma unroll
            for (int m = 1; m < 64; m <<= 1) { ka0 += __shfl_xor(ka0, m); ka1 += __shfl_xor(ka1, m); }
            if (ln == 0) { kred[wv][0] = ka0; kred[wv][1] = ka1; }
        }

        // ---- hs flush every 8 steps: each thread flushes ITS OWN row ----
        if ((t & 7) == 7) {
            const int t0 = t - 7;
            const float* tr = &tbuf[tid][0];
            f32x4 v0, v1;
            v0.x = tr[0]; v0.y = tr[1]; v0.z = tr[2]; v0.w = tr[3];
            v1.x = tr[4]; v1.y = tr[5]; v1.z = tr[6]; v1.w = tr[7];
            float* dst = out + OFF_HS + ((long)bb * HH + tid) * TN + t0;
            __builtin_nontemporal_store(v0, (f32x4*)dst);
            __builtin_nontemporal_store(v1, (f32x4*)(dst + 4));
        }
        // ---- keys/prs/tm flush every 16 steps (wave 0; same-wave ordering
        //      with thread 0's writes above) ----
        if ((t & 15) == 0 && wv == 0) {
            const int f = tile ^ 1, t0 = t - 16;
            if (ln < 8) {
                const int ch = ln >> 2, c4 = ln & 3;
                __builtin_nontemporal_store(*(const f32x4*)&keysT[f][ch][c4 * 4],
                    (f32x4*)(out + OFF_KEYS + (long)bb * 2 * TN + ch * TN + t0 + c4 * 4));
            } else if (ln < 24) {
                const int ix = ln - 8, ch = ix >> 2, c4 = ix & 3;
                __builtin_nontemporal_store(*(const f32x4*)&prsT[f][ch][c4 * 4],
                    (f32x4*)(out + OFF_PRS + (long)bb * 4 * TN + ch * TN + t0 + c4 * 4));
            } else if (ln < 28) {
                const int c4 = ln - 24;
                __builtin_nontemporal_store(*(const f32x4*)&tmT[f][c4 * 4],
                    (f32x4*)(out + OFF_TM + (long)bb * 2 * TN + TN + t0 + c4 * 4));
            }
        }
        __syncthreads();    // the ONE barrier: orders hsh[par2]/kred/tile writes
    }

    // ---------------- epilogue: key(1023) + final keys/prs/tm tile ----------------
    if (tid == 0) {
        float k0 = 0.f, k1 = 0.f;
        #pragma unroll
        for (int w = 0; w < 8; ++w) { k0 += kred[w][0]; k1 += kred[w][1]; }
        keysT[1][0][15] = sigm(k0 + bk0);
        keysT[1][1][15] = sigm(k1 + bk1);
    }
    __syncthreads();
    if (wv == 0) {
        const int f = 1, t0 = TN - 16;
        if (ln < 8) {
            const int ch = ln >> 2, c4 = ln & 3;
            __builtin_nontemporal_store(*(const f32x4*)&keysT[f][ch][c4 * 4],
                (f32x4*)(out + OFF_KEYS + (long)bb * 2 * TN + ch * TN + t0 + c4 * 4));
        } else if (ln < 24) {
            const int ix = ln - 8, ch = ix >> 2, c4 = ix & 3;
            __builtin_nontemporal_store(*(const f32x4*)&prsT[f][ch][c4 * 4],
                (f32x4*)(out + OFF_PRS + (long)bb * 4 * TN + ch * TN + t0 + c4 * 4));
        } else if (ln < 28) {
            const int c4 = ln - 24;
            __builtin_nontemporal_store(*(const f32x4*)&tmT[f][c4 * 4],
                (f32x4*)(out + OFF_TM + (long)bb * 2 * TN + TN + t0 + c4 * 4));
        }
    }
}

extern "C" void kernel_launch(void* const* d_in, const int* in_sizes, int n_in,
                              void* d_out, int out_size, void* d_ws, size_t ws_size,
                              hipStream_t stream) {
    (void)in_sizes; (void)n_in; (void)out_size; (void)ws_size;
    const float* in    = (const float*)d_in[0];
    const float* w_in  = (const float*)d_in[1];
    const float* b_in  = (const float*)d_in[2];
    const float* w_rec = (const float*)d_in[3];
    const float* b_rec = (const float*)d_in[4];
    const float* w_key = (const float*)d_in[5];
    const float* b_key = (const float*)d_in[6];
    const float* z     = (const float*)d_in[7];
    float* out = (float*)d_out;
    _Float16* whf = (_Float16*)d_ws;     // 512 KB scratch

    hipLaunchKernelGGL(conv_fp16, dim3(HH * HH / 1024), dim3(256), 0, stream, w_rec, whf);
    hipLaunchKernelGGL(rnn_fused, dim3(BB), dim3(NTHR), 0, stream,
                       in, w_in, b_in, b_rec, w_key, b_key, z, out, whf);
}